// Round 15
// baseline (337.853 us; speedup 1.0000x reference)
//
#include <hip/hip_runtime.h>
#include <hip/hip_fp16.h>
#include <math.h>

#define HH 128
#define WW 128
#define BB 4
#define HWSZ (HH*WW)
#define PW 130          // padded image width/height
#define PSZ (PW*PW)     // 16900 padded pixels

typedef _Float16 half_t;
typedef half_t half2v __attribute__((ext_vector_type(2)));
typedef half_t half4v __attribute__((ext_vector_type(4)));
typedef half_t half8 __attribute__((ext_vector_type(8)));
typedef float  f32x16 __attribute__((ext_vector_type(16)));

__device__ __forceinline__ float lrelu_f(float v) { return v >= 0.0f ? v : 0.1f * v; }
// fast tanh/sigmoid via v_exp_f32 (~1e-5 rel err; offset err <=2e-4 px,
// far below the 2^-7 off4-quantization absmax floor)
__device__ __forceinline__ float tanh_fast(float x) {
    float t = __expf(2.0f * x);
    return (t - 1.0f) / (t + 1.0f);
}
__device__ __forceinline__ float sigmoid_fast(float x) {
    return 1.0f / (1.0f + __expf(-x));
}

// ---------------------------------------------------------------------------
// pack A0 via LDS transpose. Each block: 64 padded pixels x 144 ch.
// Single fp16 plane, layout [pp][144].
// ---------------------------------------------------------------------------
__global__ __launch_bounds__(256)
void pack_a0_k(const float* __restrict__ xfw, const float* __restrict__ xc,
               const float* __restrict__ flow, half_t* __restrict__ a0)
{
    __shared__ float s[64][145];
    const int tid = threadIdx.x;
    const int p0 = blockIdx.x * 64;                     // global padded pixel base
    for (int i = tid; i < 64 * 144; i += 256) {
        int c = i >> 6, px = i & 63;
        int pp = p0 + px;
        float v = 0.0f;
        if (pp < BB * PSZ) {
            int b = pp / PSZ; int p = pp - b * PSZ;
            int yy = p / PW, xx = p - yy * PW;
            if (yy >= 1 && yy <= HH && xx >= 1 && xx <= WW) {
                int pi = (yy - 1) * WW + (xx - 1);
                if (c < 64)       v = xfw[(size_t)(b*64 + c) * HWSZ + pi];
                else if (c < 128) v = xc [(size_t)(b*64 + c - 64) * HWSZ + pi];
                else if (c < 130) v = flow[(size_t)(b*2 + c - 128) * HWSZ + pi];
            }
        }
        s[px][c] = v;
    }
    __syncthreads();
    for (int i = tid; i < 64 * 144; i += 256) {
        int px = i / 144, c = i - px * 144;
        int pp = p0 + px;
        if (pp < BB * PSZ)
            a0[(size_t)pp * 144 + c] = (half_t)s[px][c];
    }
}

// ---------------------------------------------------------------------------
// zero 1-px borders of ONE padded feature buffer [b][130x130][64] fp16.
// ---------------------------------------------------------------------------
__global__ __launch_bounds__(256)
void zero_border_k(half_t* __restrict__ hbuf)
{
    int idx = blockIdx.x * 256 + threadIdx.x;           // 2064*8 = 16512
    if (idx >= 2064 * 8) return;
    int chunk = idx & 7; int bp = idx >> 3;
    int b = bp / 516;     int rr = bp - b * 516;
    int yy, xx;
    if (rr < 130)      { yy = 0;        xx = rr; }
    else if (rr < 260) { yy = 129;      xx = rr - 130; }
    else if (rr < 388) { yy = rr - 259; xx = 0; }
    else               { yy = rr - 387; xx = 129; }
    size_t base = ((size_t)(b * PSZ + yy * PW + xx)) * 64 + chunk * 8;
    half8 z = {(half_t)0.f,(half_t)0.f,(half_t)0.f,(half_t)0.f,
               (half_t)0.f,(half_t)0.f,(half_t)0.f,(half_t)0.f};
    *(half8*)(hbuf + base) = z;
}

// ---------------------------------------------------------------------------
// pack conv weights: W[oc][cin][3][3] fp32 ->
//   Wp[ocg][kc][tap][ks][ocw<OCB][8]  (single fp16 plane; OCB = oc per block)
// ---------------------------------------------------------------------------
__global__ __launch_bounds__(256)
void pack_w_k(const float* __restrict__ w, half_t* __restrict__ wp,
              int OC, int CIN, int OCP, int CINP, int NKC, int OCB)
{
    int idx = blockIdx.x * 256 + threadIdx.x;           // OCP*CINP*9
    if (idx >= OCP * CINP * 9) return;
    int j   = idx & 7;
    int r   = idx >> 3;
    int ocw = r % OCB;  r /= OCB;
    int ks  = r & 1;    r >>= 1;
    int tap = r % 9;    r /= 9;
    int kc  = r % NKC;
    int ocg = r / NKC;
    int oc  = ocg * OCB + ocw;
    int cin = kc * 16 + ks * 8 + j;
    float v = (oc < OC && cin < CIN) ? w[((size_t)oc * CIN + cin) * 9 + tap] : 0.0f;
    wp[idx] = (half_t)v;
}

// ---------------------------------------------------------------------------
// pack dcn weights: dw[oc64][cin64][3][3] -> Bp[dg16][ks3][oc64][16] fp16
// ---------------------------------------------------------------------------
__global__ __launch_bounds__(256)
void pack_dw_k(const float* __restrict__ dw, half_t* __restrict__ Bp)
{
    int idx = blockIdx.x * 256 + threadIdx.x;           // 16*3*64*16 = 49152
    if (idx >= 16 * 3 * 64 * 16) return;
    int kj = idx & 15;
    int oc = (idx >> 4) & 63;
    int r  = idx >> 10;
    int ks = r % 3;
    int dg = r / 3;
    int tap = ks * 4 + (kj >> 2);
    int cg  = kj & 3;
    float v = (tap < 9) ? dw[((size_t)oc * 64 + dg*4 + cg) * 9 + tap] : 0.0f;
    Bp[idx] = (half_t)v;
}

// ---------------------------------------------------------------------------
// transpose x NCHW fp32 -> xTh fp16 dg-major [dg16][b][pix][4ch]
// ---------------------------------------------------------------------------
__global__ __launch_bounds__(256)
void pack_xt_k(const float* __restrict__ x, half_t* __restrict__ xTh)
{
    __shared__ float s[64][65];
    const int tid = threadIdx.x;
    const int p0 = blockIdx.x * 64;
    const int b = p0 >> 14, pp = p0 & 16383;
    for (int i = tid; i < 4096; i += 256) {
        int c = i >> 6, p = i & 63;
        s[p][c] = x[((size_t)(b*64 + c) << 14) + pp + p];
    }
    __syncthreads();
    for (int i = tid; i < 1024; i += 256) {
        int dg = i >> 6, p = i & 63;
        half4v v = { (half_t)s[p][dg*4+0], (half_t)s[p][dg*4+1],
                     (half_t)s[p][dg*4+2], (half_t)s[p][dg*4+3] };
        *(half4v*)(xTh + ((size_t)(dg*BB + b) * HWSZ + pp + p) * 4) = v;
    }
}

// ---------------------------------------------------------------------------
// MFMA implicit-GEMM 3x3 SAME conv, single-fp16 A and B. r14 config kept
// (conv4 MT=1 NT=2 z=7 (256,8); conv1-3 NT=2 (256,4)). r15: epilogue
// transcendentals -> __expf-based fast forms (libm tanhf ~40 instr -> 5;
// 32 per thread sat between the final barriers at VALUBusy 37%).
// ---------------------------------------------------------------------------
template<int CINP, int MT, int EPI, int NT>
__global__ __launch_bounds__(256, (EPI == 1 ? 8 : 4))
void conv_mfma_k(const half_t* __restrict__ A, const half_t* __restrict__ Wp,
                 const float* __restrict__ bias, void* __restrict__ outv,
                 int OC, const float* __restrict__ flow)
{
    constexpr int NKC   = CINP / 16;
    constexpr int PSTR  = 24;
    constexpr int PROWS = 8 * MT;
    constexpr int HALO  = (PROWS + 2) * 18;
    constexpr int NCH_A = HALO * 2;           // A 16B chunks per kc (single plane)
    constexpr int OCB   = NT * 32;            // output channels per block
    constexpr int NCH_B = 9 * 2 * OCB;        // B 16B chunks per kc
    const int tid  = threadIdx.x;
    const int lane = tid & 63;
    const int wv   = tid >> 6;
    const int b     = blockIdx.y;
    const int patch = blockIdx.x;
    const int y0 = (patch >> 3) * PROWS;
    const int x0 = (patch & 7) * 16;
    const int ocBase = blockIdx.z * OCB;

    __shared__ __align__(16) half_t s_a[HALO * PSTR];
    __shared__ __align__(16) half_t s_b[NCH_B * 8];

    f32x16 acc[MT][NT];
#pragma unroll
    for (int mt = 0; mt < MT; ++mt)
#pragma unroll
        for (int nt = 0; nt < NT; ++nt)
#pragma unroll
            for (int r = 0; r < 16; ++r) acc[mt][nt][r] = 0.0f;

    const int m     = lane & 31;
    const int klane = lane >> 5;
    const int row0  = wv * 2 * MT + (m >> 4);
    const int pxx   = m & 15;
    int abase[MT];
#pragma unroll
    for (int mt = 0; mt < MT; ++mt)
        abase[mt] = ((row0 + 2*mt) * 18 + pxx) * PSTR + klane * 8;

    const half_t* Ab = A + (size_t)b * PSZ * CINP;

    for (int kc = 0; kc < NKC; ++kc) {
        __syncthreads();
        // stage B slice ASYNC (global->LDS DMA)
        {
            const half_t* wsrc = Wp + ((size_t)(blockIdx.z * NKC + kc) * NCH_B) * 8;
#pragma unroll
            for (int i = tid; i < NCH_B; i += 256)
                __builtin_amdgcn_global_load_lds(
                    (const __attribute__((address_space(1))) void*)(wsrc + i * 8),
                    (__attribute__((address_space(3))) void*)(s_b + i * 8),
                    16, 0, 0);
        }
        // stage A halo k-chunk (manual; overlaps B DMA)
        for (int i = tid; i < NCH_A; i += 256) {
            int pix = i >> 1, half = i & 1;
            int hy = pix / 18, hx = pix - hy * 18;
            const half_t* src = Ab + (size_t)((y0 + hy) * PW + x0 + hx) * CINP
                                + kc * 16 + half * 8;
            *(half8*)(s_a + pix * PSTR + half * 8) = *(const half8*)src;
        }
        __syncthreads();

#pragma unroll
        for (int tap = 0; tap < 9; ++tap) {
            const int aoff = ((tap / 3) * 18 + (tap % 3)) * PSTR;
            half8 Bh[NT];
#pragma unroll
            for (int nt = 0; nt < NT; ++nt)
                Bh[nt] = *(const half8*)(s_b + (((tap*2 + klane)*OCB + nt*32 + m)*8));
#pragma unroll
            for (int mt = 0; mt < MT; ++mt) {
                half8 Ah = *(const half8*)(s_a + abase[mt] + aoff);
#pragma unroll
                for (int nt = 0; nt < NT; ++nt)
                    acc[mt][nt] = __builtin_amdgcn_mfma_f32_32x32x16_f16(Ah, Bh[nt], acc[mt][nt], 0,0,0);
            }
        }
    }

    if (EPI == 0) {
#pragma unroll
        for (int nt = 0; nt < NT; ++nt) {
            const int oc = ocBase + nt * 32 + m;
            const float bv = bias[oc];
#pragma unroll
            for (int mt = 0; mt < MT; ++mt) {
#pragma unroll
                for (int r = 0; r < 16; ++r) {
                    const int row = (r & 3) + 8 * (r >> 2) + 4 * klane;
                    const int pyy = wv * 2 * MT + mt * 2 + (row >> 4);
                    const int gy = y0 + pyy, gx = x0 + (row & 15);
                    float v = lrelu_f(acc[mt][nt][r] + bv);
                    half_t* o = (half_t*)outv;
                    o[((size_t)(b * PSZ + (gy + 1) * PW + (gx + 1))) * 64 + oc] = (half_t)v;
                }
            }
        }
    } else {
        // coalesced epilogue: per 32-oc pass, stage fp16 tile [32 oc][PROWS][16 gx]
        constexpr int EPC = 32 * PROWS * 2;    // half8 chunks per pass
        half_t* s_ep = s_b;                    // reuse (<=16.9KB <= NCH_B*16)
        half_t* o = (half_t*)outv;
#pragma unroll
        for (int nt = 0; nt < NT; ++nt) {
            __syncthreads();                   // s_b free (kc loop / prev pass done)
            const int oc = ocBase + nt * 32 + m;
            const float bv = (oc < OC) ? bias[oc] : 0.0f;
#pragma unroll
            for (int mt = 0; mt < MT; ++mt) {
#pragma unroll
                for (int r = 0; r < 16; ++r) {
                    const int row = (r & 3) + 8 * (r >> 2) + 4 * klane;
                    const int pyy = wv * 2 * MT + mt * 2 + (row >> 4);
                    const int gxl = row & 15;
                    float v = acc[mt][nt][r] + bv;
                    if (oc < 288) {
                        const int fch = (oc & 1) ^ 1;
                        float fl = flow[(size_t)(b*2 + fch) * HWSZ + (y0+pyy) * WW + (x0+gxl)];
                        v = 10.0f * tanh_fast(v) + fl;
                    } else {
                        v = sigmoid_fast(v);
                    }
                    s_ep[m * 264 + pyy * 16 + gxl] = (half_t)v;
                }
            }
            __syncthreads();
            for (int c = tid; c < EPC; c += 256) {
                int ocl = c / (PROWS * 2), rem = c % (PROWS * 2);
                int row = rem >> 1, hf = rem & 1;
                int ocg = ocBase + nt * 32 + ocl;
                if (ocg < OC) {
                    half8 vv = *(const half8*)(s_ep + ocl * 264 + row * 16 + hf * 8);
                    *(half8*)(o + ((size_t)(b * 432 + ocg) << 14) + (y0 + row) * 128 + x0 + hf * 8) = vv;
                }
            }
        }
    }
}

// ---------------------------------------------------------------------------
// dcn, dg-split + XCD-partitioned grid + zero-padded window (r13-proven).
// Unchanged this round.
// ---------------------------------------------------------------------------
__global__ __launch_bounds__(256, 4)
void dcn_mfma_k(const half_t* __restrict__ xTh, const __half* __restrict__ off4,
                const half_t* __restrict__ Bp, const float* __restrict__ bias,
                float* __restrict__ out, half_t* __restrict__ p1h)
{
    constexpr int HLO = 24;
    constexpr int WR  = 4 + 2 * HLO;    // 52 window rows
    constexpr int WC  = 32 + 2 * HLO;   // 80 window cols
    constexpr int NWIN = WR * WC;       // 4160 records
    __shared__ __align__(16) char smem[64 * 132 * 4];  // 33,792B union
    half4v* s_x = (half4v*)smem;                       // 4160 recs (33,280B)
    float*  s_t = (float*)smem;                        // 64 oc x 132

    const int tid   = threadIdx.x;
    const int lane  = tid & 63;
    const int wv    = tid >> 6;
    const int klane = lane >> 5;
    const int m     = lane & 31;
    const int zz    = blockIdx.x;       // (b,half): fastest axis -> XCD-partitioned
    const int b     = zz >> 1;
    const int dgbase = (zz & 1) * 8;
    const int tx0 = blockIdx.y * 32, ty0 = blockIdx.z * 4;
    const int py = ty0 + wv;
    const int px = tx0 + m;
    const int pixoff = py * WW + px;

    const __half* offb = off4 + (size_t)b * 432 * HWSZ;

    f32x16 acc[2];
#pragma unroll
    for (int nt = 0; nt < 2; ++nt)
#pragma unroll
        for (int r = 0; r < 16; ++r) acc[nt][r] = 0.0f;

    for (int dgi = 0; dgi < 8; ++dgi) {
        const int dg = dgbase + dgi;
        const half_t* xdg = xTh + ((size_t)(dg * BB + b) * HWSZ) * 4;
        __syncthreads();                                   // prior dg reads done
        for (int i = tid; i < NWIN; i += 256) {
            int wr = i / WC, wc = i - wr * WC;
            int ry = ty0 - HLO + wr;
            int cx = tx0 - HLO + wc;
            half4v v = {};
            if ((unsigned)ry < (unsigned)HH && (unsigned)cx < (unsigned)WW)
                v = *(const half4v*)(xdg + ((size_t)ry * WW + cx) * 4);
            s_x[i] = v;
        }
        __syncthreads();

        const half_t* bbase = Bp + (size_t)(dg * 3) * 64 * 16;
#pragma unroll
        for (int ks = 0; ks < 3; ++ks) {
            half2v svp[2][2] = {};
#pragma unroll
            for (int tt = 0; tt < 2; ++tt) {
                const int tap = ks * 4 + klane * 2 + tt;
                if (tap < 9) {
                    const int ch = dg * 9 + tap;
                    float oy = __half2float(offb[(size_t)(2*ch    ) * HWSZ + pixoff]);
                    float ox = __half2float(offb[(size_t)(2*ch + 1) * HWSZ + pixoff]);
                    float mk = __half2float(offb[(size_t)(288 + ch) * HWSZ + pixoff]);
                    float ys = (float)(py + tap / 3 - 1) + oy;
                    float xs = (float)(px + tap % 3 - 1) + ox;
                    float y0f = floorf(ys), x0f = floorf(xs);
                    float wy = ys - y0f,    wx = xs - x0f;
                    int y0 = (int)y0f, x0i = (int)x0f;
                    float a0 = (1.0f - wy) * mk, a1 = wy * mk;
                    float w00 = a0 * (1.0f - wx), w01 = a0 * wx;
                    float w10 = a1 * (1.0f - wx), w11 = a1 * wx;
                    const int wr0 = y0  - (ty0 - HLO);
                    const int wc0 = x0i - (tx0 - HLO);
                    half4v c00, c01, c10, c11;
                    if ((unsigned)wr0 < (unsigned)(WR - 1) &&
                        (unsigned)wc0 < (unsigned)(WC - 1)) {
                        const half4v* pw = s_x + wr0 * WC + wc0;
                        c00 = pw[0];  c01 = pw[1];
                        c10 = pw[WC]; c11 = pw[WC + 1];
                    } else {
                        int y1 = y0 + 1, x1 = x0i + 1;
                        float fy0 = (y0  >= 0 && y0  < HH) ? 1.0f : 0.0f;
                        float fy1 = (y1  >= 0 && y1  < HH) ? 1.0f : 0.0f;
                        float fx0 = (x0i >= 0 && x0i < WW) ? 1.0f : 0.0f;
                        float fx1 = (x1  >= 0 && x1  < WW) ? 1.0f : 0.0f;
                        int yc0 = min(max(y0, 0), HH-1), yc1 = min(max(y1, 0), HH-1);
                        int xc0 = min(max(x0i,0), WW-1), xc1 = min(max(x1, 0), WW-1);
                        w00 *= fy0 * fx0; w01 *= fy0 * fx1;
                        w10 *= fy1 * fx0; w11 *= fy1 * fx1;
                        c00 = *(const half4v*)(xdg + ((size_t)yc0 * WW + xc0) * 4);
                        c01 = *(const half4v*)(xdg + ((size_t)yc0 * WW + xc1) * 4);
                        c10 = *(const half4v*)(xdg + ((size_t)yc1 * WW + xc0) * 4);
                        c11 = *(const half4v*)(xdg + ((size_t)yc1 * WW + xc1) * 4);
                    }
                    half_t h00 = (half_t)w00, h01 = (half_t)w01;
                    half_t h10 = (half_t)w10, h11 = (half_t)w11;
                    half2v W00 = {h00, h00}, W01 = {h01, h01};
                    half2v W10 = {h10, h10}, W11 = {h11, h11};
                    half2v lo = __builtin_shufflevector(c00, c00, 0, 1) * W00
                              + __builtin_shufflevector(c01, c01, 0, 1) * W01
                              + __builtin_shufflevector(c10, c10, 0, 1) * W10
                              + __builtin_shufflevector(c11, c11, 0, 1) * W11;
                    half2v hi = __builtin_shufflevector(c00, c00, 2, 3) * W00
                              + __builtin_shufflevector(c01, c01, 2, 3) * W01
                              + __builtin_shufflevector(c10, c10, 2, 3) * W10
                              + __builtin_shufflevector(c11, c11, 2, 3) * W11;
                    svp[tt][0] = lo; svp[tt][1] = hi;
                }
            }
            half8 a;
            a[0] = svp[0][0][0]; a[1] = svp[0][0][1];
            a[2] = svp[0][1][0]; a[3] = svp[0][1][1];
            a[4] = svp[1][0][0]; a[5] = svp[1][0][1];
            a[6] = svp[1][1][0]; a[7] = svp[1][1][1];
            // consume immediately (short live range for the fragment)
#pragma unroll
            for (int nt = 0; nt < 2; ++nt) {
                half8 Bh = *(const half8*)(bbase + ((size_t)(ks*64 + nt*32 + m)) * 16 + klane*8);
                acc[nt] = __builtin_amdgcn_mfma_f32_32x32x16_f16(a, Bh, acc[nt], 0,0,0);
            }
        }
        __syncthreads();                                   // compute done before next stage
    }

    if (dgbase == 0) {
        // half0: +bias -> out fp32, staged through LDS for float4 stores
#pragma unroll
        for (int nt = 0; nt < 2; ++nt) {
            const int oc = nt * 32 + m;
            const float bv = bias[oc];
#pragma unroll
            for (int r = 0; r < 16; ++r) {
                const int row = (r & 3) + 8 * (r >> 2) + 4 * klane;   // px 0..31
                s_t[oc * 132 + wv * 32 + row] = acc[nt][r] + bv;
            }
        }
        __syncthreads();
        for (int c = tid; c < 2048; c += 256) {            // 64 oc x 4 row x 8 float4
            int ocl = c >> 5, rem = c & 31, row = rem >> 3, q = rem & 7;
            float4 v = *(const float4*)(s_t + ocl * 132 + row * 32 + q * 4);
            *(float4*)(out + ((size_t)(b*64 + ocl) << 14) + (ty0 + row) * 128 + tx0 + q * 4) = v;
        }
    } else {
        // half1: no bias -> p1h fp16 partial, coalesced half4 stores
#pragma unroll
        for (int nt = 0; nt < 2; ++nt) {
            const int oc = nt * 32 + m;
#pragma unroll
            for (int r = 0; r < 16; ++r) {
                const int row = (r & 3) + 8 * (r >> 2) + 4 * klane;
                s_t[oc * 132 + wv * 32 + row] = acc[nt][r];
            }
        }
        __syncthreads();
        for (int c = tid; c < 2048; c += 256) {
            int ocl = c >> 5, rem = c & 31, row = rem >> 3, q = rem & 7;
            float4 v = *(const float4*)(s_t + ocl * 132 + row * 32 + q * 4);
            half4v h = {(half_t)v.x, (half_t)v.y, (half_t)v.z, (half_t)v.w};
            *(half4v*)(p1h + ((size_t)(b*64 + ocl) << 14) + (ty0 + row) * 128 + tx0 + q * 4) = h;
        }
    }
}

// ---------------------------------------------------------------------------
// out += p1h (fp16 partial from dg half1). 42MB traffic, ~8us.
// ---------------------------------------------------------------------------
__global__ __launch_bounds__(256)
void add_partial_k(float* __restrict__ out, const half_t* __restrict__ p1h)
{
    const int N4 = BB * 64 * HWSZ / 4;                  // 1,048,576 quads
    for (int i = blockIdx.x * 256 + threadIdx.x; i < N4; i += gridDim.x * 256) {
        float4 o = *(const float4*)(out + (size_t)i * 4);
        half4v p = *(const half4v*)(p1h + (size_t)i * 4);
        o.x += (float)p[0]; o.y += (float)p[1];
        o.z += (float)p[2]; o.w += (float)p[3];
        *(float4*)(out + (size_t)i * 4) = o;
    }
}

// ---------------------------------------------------------------------------
// Workspace (~76 MB):
//   [0, 56.6MB)   off4h (fp16). Aliased during conv chain:
//       A0  @ +0      (19.5MB single-plane, live pack_a0..conv1)
//       h2p @ +0      (8.65MB single-plane, live conv2..conv3)
//   [56.6, 73.9MB) h1p region (h1p 8.65MB; after conv4: xTh (8.39MB) @ +0
//                  and p1h (8.39MB) @ +8.39MB)
//   [73.9MB, ...)  packed weights (wp1..wp4, Bp)
// ---------------------------------------------------------------------------
extern "C" void kernel_launch(void* const* d_in, const int* in_sizes, int n_in,
                              void* d_out, int out_size, void* d_ws, size_t ws_size,
                              hipStream_t stream)
{
    const float* x    = (const float*)d_in[0];
    const float* xfw  = (const float*)d_in[1];
    const float* xc   = (const float*)d_in[2];
    const float* flow = (const float*)d_in[3];
    const float* w1 = (const float*)d_in[4];  const float* b1 = (const float*)d_in[5];
    const float* w2 = (const float*)d_in[6];  const float* b2 = (const float*)d_in[7];
    const float* w3 = (const float*)d_in[8];  const float* b3 = (const float*)d_in[9];
    const float* w4 = (const float*)d_in[10]; const float* b4 = (const float*)d_in[11];
    const float* dw = (const float*)d_in[12]; const float* db = (const float*)d_in[13];

    char* wsb = (char*)d_ws;
    const size_t off4_bytes = (size_t)BB * 432 * HWSZ * 2;      // 56,623,104 (fp16)
    __half* off4 = (__half*)wsb;
    half_t* A0   = (half_t*)wsb;                                // live pack_a0..conv1
    half_t* h2p  = (half_t*)wsb;                                // live conv2..conv3
    char* p = wsb + off4_bytes;
    half_t* h1p = (half_t*)p;
    half_t* xTh = (half_t*)h1p;                                 // 8.39MB, post-conv4
    half_t* p1h = (half_t*)((char*)h1p + (size_t)BB * 64 * HWSZ * 2); // 8.39MB partial
                               p += (size_t)BB * PSZ * 2 * 64 * 2;     // region kept 17.3MB
    half_t* wp1 = (half_t*)p;  p += (size_t)64  * 144 * 9 * 2;
    half_t* wp2 = (half_t*)p;  p += (size_t)64  * 64  * 9 * 2;
    half_t* wp3 = (half_t*)p;  p += (size_t)64  * 64  * 9 * 2;
    half_t* wp4 = (half_t*)p;  p += (size_t)448 * 64  * 9 * 2;  // OCP=448 (OCB=64 x 7)
    half_t* Bp  = (half_t*)p;  p += (size_t)16 * 3 * 64 * 16 * 2;

    zero_border_k<<<(2064*8 + 255)/256, 256, 0, stream>>>(h1p);
    pack_w_k<<<(64*144*9 + 255)/256, 256, 0, stream>>>(w1, wp1, 64, 130, 64, 144, 9, 64);
    pack_w_k<<<(64*64*9  + 255)/256, 256, 0, stream>>>(w2, wp2, 64, 64, 64, 64, 4, 64);
    pack_w_k<<<(64*64*9  + 255)/256, 256, 0, stream>>>(w3, wp3, 64, 64, 64, 64, 4, 64);
    pack_w_k<<<(448*64*9 + 255)/256, 256, 0, stream>>>(w4, wp4, 432, 64, 448, 64, 4, 64);
    pack_dw_k<<<(16*3*64*16 + 255)/256, 256, 0, stream>>>(dw, Bp);
    pack_a0_k<<<(BB*PSZ + 63)/64, 256, 0, stream>>>(xfw, xc, flow, A0);

    // conv chain: conv1-3 MT=1 NT=2 (256,4); conv4 MT=1 NT=2 z=7 (256,8)
    conv_mfma_k<144,1,0,2><<<dim3(128, BB, 1), 256, 0, stream>>>(A0,  wp1, b1, h1p, 64,  nullptr);
    zero_border_k<<<(2064*8 + 255)/256, 256, 0, stream>>>(h2p);    // A0 dead now
    conv_mfma_k<64, 1,0,2><<<dim3(128, BB, 1), 256, 0, stream>>>(h1p, wp2, b2, h2p, 64,  nullptr);
    conv_mfma_k<64, 1,0,2><<<dim3(128, BB, 1), 256, 0, stream>>>(h2p, wp3, b3, h1p, 64,  nullptr);
    conv_mfma_k<64, 1,1,2><<<dim3(128, BB, 7), 256, 0, stream>>>(h1p, wp4, b4, off4, 432, flow);
    // xTh overwrites h1p (dead after conv4)
    pack_xt_k<<<BB * HWSZ / 64, 256, 0, stream>>>(x, xTh);

    // dcn: (b,half) on blockIdx.x -> one XCD per (b,half); tiles on y/z
    dcn_mfma_k<<<dim3(BB*2, 4, 32), 256, 0, stream>>>(xTh, off4, Bp, db, (float*)d_out, p1h);
    add_partial_k<<<2048, 256, 0, stream>>>((float*)d_out, p1h);
}

// Round 16
// 327.982 us; speedup vs baseline: 1.0301x; 1.0301x over previous
//
#include <hip/hip_runtime.h>
#include <hip/hip_fp16.h>
#include <math.h>

#define HH 128
#define WW 128
#define BB 4
#define HWSZ (HH*WW)
#define PW 130          // padded image width/height
#define PSZ (PW*PW)     // 16900 padded pixels

typedef _Float16 half_t;
typedef half_t half2v __attribute__((ext_vector_type(2)));
typedef half_t half4v __attribute__((ext_vector_type(4)));
typedef half_t half8 __attribute__((ext_vector_type(8)));
typedef float  f32x16 __attribute__((ext_vector_type(16)));

__device__ __forceinline__ float lrelu_f(float v) { return v >= 0.0f ? v : 0.1f * v; }
// fast tanh/sigmoid via v_exp_f32 (~1e-5 rel err; offset err <=2e-4 px,
// far below the 2^-7 off4-quantization absmax floor)
__device__ __forceinline__ float tanh_fast(float x) {
    float t = __expf(2.0f * x);
    return (t - 1.0f) / (t + 1.0f);
}
__device__ __forceinline__ float sigmoid_fast(float x) {
    return 1.0f / (1.0f + __expf(-x));
}

// ---------------------------------------------------------------------------
// pack A0 via LDS transpose. Each block: 64 padded pixels x 144 ch.
// Single fp16 plane, layout [pp][144].
// ---------------------------------------------------------------------------
__global__ __launch_bounds__(256)
void pack_a0_k(const float* __restrict__ xfw, const float* __restrict__ xc,
               const float* __restrict__ flow, half_t* __restrict__ a0)
{
    __shared__ float s[64][145];
    const int tid = threadIdx.x;
    const int p0 = blockIdx.x * 64;                     // global padded pixel base
    for (int i = tid; i < 64 * 144; i += 256) {
        int c = i >> 6, px = i & 63;
        int pp = p0 + px;
        float v = 0.0f;
        if (pp < BB * PSZ) {
            int b = pp / PSZ; int p = pp - b * PSZ;
            int yy = p / PW, xx = p - yy * PW;
            if (yy >= 1 && yy <= HH && xx >= 1 && xx <= WW) {
                int pi = (yy - 1) * WW + (xx - 1);
                if (c < 64)       v = xfw[(size_t)(b*64 + c) * HWSZ + pi];
                else if (c < 128) v = xc [(size_t)(b*64 + c - 64) * HWSZ + pi];
                else if (c < 130) v = flow[(size_t)(b*2 + c - 128) * HWSZ + pi];
            }
        }
        s[px][c] = v;
    }
    __syncthreads();
    for (int i = tid; i < 64 * 144; i += 256) {
        int px = i / 144, c = i - px * 144;
        int pp = p0 + px;
        if (pp < BB * PSZ)
            a0[(size_t)pp * 144 + c] = (half_t)s[px][c];
    }
}

// ---------------------------------------------------------------------------
// zero 1-px borders of ONE padded feature buffer [b][130x130][64] fp16.
// ---------------------------------------------------------------------------
__global__ __launch_bounds__(256)
void zero_border_k(half_t* __restrict__ hbuf)
{
    int idx = blockIdx.x * 256 + threadIdx.x;           // 2064*8 = 16512
    if (idx >= 2064 * 8) return;
    int chunk = idx & 7; int bp = idx >> 3;
    int b = bp / 516;     int rr = bp - b * 516;
    int yy, xx;
    if (rr < 130)      { yy = 0;        xx = rr; }
    else if (rr < 260) { yy = 129;      xx = rr - 130; }
    else if (rr < 388) { yy = rr - 259; xx = 0; }
    else               { yy = rr - 387; xx = 129; }
    size_t base = ((size_t)(b * PSZ + yy * PW + xx)) * 64 + chunk * 8;
    half8 z = {(half_t)0.f,(half_t)0.f,(half_t)0.f,(half_t)0.f,
               (half_t)0.f,(half_t)0.f,(half_t)0.f,(half_t)0.f};
    *(half8*)(hbuf + base) = z;
}

// ---------------------------------------------------------------------------
// pack conv weights: W[oc][cin][3][3] fp32 ->
//   Wp[ocg][kc][tap][ks][ocw<OCB][8]  (single fp16 plane; OCB = oc per block)
// ---------------------------------------------------------------------------
__global__ __launch_bounds__(256)
void pack_w_k(const float* __restrict__ w, half_t* __restrict__ wp,
              int OC, int CIN, int OCP, int CINP, int NKC, int OCB)
{
    int idx = blockIdx.x * 256 + threadIdx.x;           // OCP*CINP*9
    if (idx >= OCP * CINP * 9) return;
    int j   = idx & 7;
    int r   = idx >> 3;
    int ocw = r % OCB;  r /= OCB;
    int ks  = r & 1;    r >>= 1;
    int tap = r % 9;    r /= 9;
    int kc  = r % NKC;
    int ocg = r / NKC;
    int oc  = ocg * OCB + ocw;
    int cin = kc * 16 + ks * 8 + j;
    float v = (oc < OC && cin < CIN) ? w[((size_t)oc * CIN + cin) * 9 + tap] : 0.0f;
    wp[idx] = (half_t)v;
}

// ---------------------------------------------------------------------------
// pack dcn weights: dw[oc64][cin64][3][3] -> Bp[dg16][ks3][oc64][16] fp16
// ---------------------------------------------------------------------------
__global__ __launch_bounds__(256)
void pack_dw_k(const float* __restrict__ dw, half_t* __restrict__ Bp)
{
    int idx = blockIdx.x * 256 + threadIdx.x;           // 16*3*64*16 = 49152
    if (idx >= 16 * 3 * 64 * 16) return;
    int kj = idx & 15;
    int oc = (idx >> 4) & 63;
    int r  = idx >> 10;
    int ks = r % 3;
    int dg = r / 3;
    int tap = ks * 4 + (kj >> 2);
    int cg  = kj & 3;
    float v = (tap < 9) ? dw[((size_t)oc * 64 + dg*4 + cg) * 9 + tap] : 0.0f;
    Bp[idx] = (half_t)v;
}

// ---------------------------------------------------------------------------
// transpose x NCHW fp32 -> xTh fp16 dg-major [dg16][b][pix][4ch]
// ---------------------------------------------------------------------------
__global__ __launch_bounds__(256)
void pack_xt_k(const float* __restrict__ x, half_t* __restrict__ xTh)
{
    __shared__ float s[64][65];
    const int tid = threadIdx.x;
    const int p0 = blockIdx.x * 64;
    const int b = p0 >> 14, pp = p0 & 16383;
    for (int i = tid; i < 4096; i += 256) {
        int c = i >> 6, p = i & 63;
        s[p][c] = x[((size_t)(b*64 + c) << 14) + pp + p];
    }
    __syncthreads();
    for (int i = tid; i < 1024; i += 256) {
        int dg = i >> 6, p = i & 63;
        half4v v = { (half_t)s[p][dg*4+0], (half_t)s[p][dg*4+1],
                     (half_t)s[p][dg*4+2], (half_t)s[p][dg*4+3] };
        *(half4v*)(xTh + ((size_t)(dg*BB + b) * HWSZ + pp + p) * 4) = v;
    }
}

// ---------------------------------------------------------------------------
// MFMA implicit-GEMM 3x3 SAME conv, single-fp16 A and B. r14 config kept
// (conv4 MT=1 NT=2 z=7 (256,8); conv1-3 NT=2 (256,4)); fast-exp epilogue.
// ---------------------------------------------------------------------------
template<int CINP, int MT, int EPI, int NT>
__global__ __launch_bounds__(256, (EPI == 1 ? 8 : 4))
void conv_mfma_k(const half_t* __restrict__ A, const half_t* __restrict__ Wp,
                 const float* __restrict__ bias, void* __restrict__ outv,
                 int OC, const float* __restrict__ flow)
{
    constexpr int NKC   = CINP / 16;
    constexpr int PSTR  = 24;
    constexpr int PROWS = 8 * MT;
    constexpr int HALO  = (PROWS + 2) * 18;
    constexpr int NCH_A = HALO * 2;           // A 16B chunks per kc (single plane)
    constexpr int OCB   = NT * 32;            // output channels per block
    constexpr int NCH_B = 9 * 2 * OCB;        // B 16B chunks per kc
    const int tid  = threadIdx.x;
    const int lane = tid & 63;
    const int wv   = tid >> 6;
    const int b     = blockIdx.y;
    const int patch = blockIdx.x;
    const int y0 = (patch >> 3) * PROWS;
    const int x0 = (patch & 7) * 16;
    const int ocBase = blockIdx.z * OCB;

    __shared__ __align__(16) half_t s_a[HALO * PSTR];
    __shared__ __align__(16) half_t s_b[NCH_B * 8];

    f32x16 acc[MT][NT];
#pragma unroll
    for (int mt = 0; mt < MT; ++mt)
#pragma unroll
        for (int nt = 0; nt < NT; ++nt)
#pragma unroll
            for (int r = 0; r < 16; ++r) acc[mt][nt][r] = 0.0f;

    const int m     = lane & 31;
    const int klane = lane >> 5;
    const int row0  = wv * 2 * MT + (m >> 4);
    const int pxx   = m & 15;
    int abase[MT];
#pragma unroll
    for (int mt = 0; mt < MT; ++mt)
        abase[mt] = ((row0 + 2*mt) * 18 + pxx) * PSTR + klane * 8;

    const half_t* Ab = A + (size_t)b * PSZ * CINP;

    for (int kc = 0; kc < NKC; ++kc) {
        __syncthreads();
        // stage B slice ASYNC (global->LDS DMA)
        {
            const half_t* wsrc = Wp + ((size_t)(blockIdx.z * NKC + kc) * NCH_B) * 8;
#pragma unroll
            for (int i = tid; i < NCH_B; i += 256)
                __builtin_amdgcn_global_load_lds(
                    (const __attribute__((address_space(1))) void*)(wsrc + i * 8),
                    (__attribute__((address_space(3))) void*)(s_b + i * 8),
                    16, 0, 0);
        }
        // stage A halo k-chunk (manual; overlaps B DMA)
        for (int i = tid; i < NCH_A; i += 256) {
            int pix = i >> 1, half = i & 1;
            int hy = pix / 18, hx = pix - hy * 18;
            const half_t* src = Ab + (size_t)((y0 + hy) * PW + x0 + hx) * CINP
                                + kc * 16 + half * 8;
            *(half8*)(s_a + pix * PSTR + half * 8) = *(const half8*)src;
        }
        __syncthreads();

#pragma unroll
        for (int tap = 0; tap < 9; ++tap) {
            const int aoff = ((tap / 3) * 18 + (tap % 3)) * PSTR;
            half8 Bh[NT];
#pragma unroll
            for (int nt = 0; nt < NT; ++nt)
                Bh[nt] = *(const half8*)(s_b + (((tap*2 + klane)*OCB + nt*32 + m)*8));
#pragma unroll
            for (int mt = 0; mt < MT; ++mt) {
                half8 Ah = *(const half8*)(s_a + abase[mt] + aoff);
#pragma unroll
                for (int nt = 0; nt < NT; ++nt)
                    acc[mt][nt] = __builtin_amdgcn_mfma_f32_32x32x16_f16(Ah, Bh[nt], acc[mt][nt], 0,0,0);
            }
        }
    }

    if (EPI == 0) {
#pragma unroll
        for (int nt = 0; nt < NT; ++nt) {
            const int oc = ocBase + nt * 32 + m;
            const float bv = bias[oc];
#pragma unroll
            for (int mt = 0; mt < MT; ++mt) {
#pragma unroll
                for (int r = 0; r < 16; ++r) {
                    const int row = (r & 3) + 8 * (r >> 2) + 4 * klane;
                    const int pyy = wv * 2 * MT + mt * 2 + (row >> 4);
                    const int gy = y0 + pyy, gx = x0 + (row & 15);
                    float v = lrelu_f(acc[mt][nt][r] + bv);
                    half_t* o = (half_t*)outv;
                    o[((size_t)(b * PSZ + (gy + 1) * PW + (gx + 1))) * 64 + oc] = (half_t)v;
                }
            }
        }
    } else {
        // coalesced epilogue: per 32-oc pass, stage fp16 tile [32 oc][PROWS][16 gx]
        constexpr int EPC = 32 * PROWS * 2;    // half8 chunks per pass
        half_t* s_ep = s_b;                    // reuse (<=16.9KB <= NCH_B*16)
        half_t* o = (half_t*)outv;
#pragma unroll
        for (int nt = 0; nt < NT; ++nt) {
            __syncthreads();                   // s_b free (kc loop / prev pass done)
            const int oc = ocBase + nt * 32 + m;
            const float bv = (oc < OC) ? bias[oc] : 0.0f;
#pragma unroll
            for (int mt = 0; mt < MT; ++mt) {
#pragma unroll
                for (int r = 0; r < 16; ++r) {
                    const int row = (r & 3) + 8 * (r >> 2) + 4 * klane;
                    const int pyy = wv * 2 * MT + mt * 2 + (row >> 4);
                    const int gxl = row & 15;
                    float v = acc[mt][nt][r] + bv;
                    if (oc < 288) {
                        const int fch = (oc & 1) ^ 1;
                        float fl = flow[(size_t)(b*2 + fch) * HWSZ + (y0+pyy) * WW + (x0+gxl)];
                        v = 10.0f * tanh_fast(v) + fl;
                    } else {
                        v = sigmoid_fast(v);
                    }
                    s_ep[m * 264 + pyy * 16 + gxl] = (half_t)v;
                }
            }
            __syncthreads();
            for (int c = tid; c < EPC; c += 256) {
                int ocl = c / (PROWS * 2), rem = c % (PROWS * 2);
                int row = rem >> 1, hf = rem & 1;
                int ocg = ocBase + nt * 32 + ocl;
                if (ocg < OC) {
                    half8 vv = *(const half8*)(s_ep + ocl * 264 + row * 16 + hf * 8);
                    *(half8*)(o + ((size_t)(b * 432 + ocg) << 14) + (y0 + row) * 128 + x0 + hf * 8) = vv;
                }
            }
        }
    }
}

// ---------------------------------------------------------------------------
// dcn. r16: off4 staged into LDS per (tile,dg) — r15 A/B proved dcn is
// latency-bound, not VALU-bound (VALU 47->37 with flat 78us): the stall is
// 18 scalar off4 loads/thread/dg (distinct 32KB-strided lines, ~250cy L2).
// Staging = 432 coalesced half8 loads/block/dg (2 contiguous channel runs),
// overlapped with s_x staging between the same barriers; taps read LDS.
// LDS 33792 -> 40960 = exactly 160KB/4 blocks (tripwire: LDS_Block_Size
// > 40960 means 3 blk/CU -> revert).
// ---------------------------------------------------------------------------
__global__ __launch_bounds__(256, 4)
void dcn_mfma_k(const half_t* __restrict__ xTh, const __half* __restrict__ off4,
                const half_t* __restrict__ Bp, const float* __restrict__ bias,
                float* __restrict__ out, half_t* __restrict__ p1h)
{
    constexpr int HLO = 24;
    constexpr int WR  = 4 + 2 * HLO;    // 52 window rows
    constexpr int WC  = 32 + 2 * HLO;   // 80 window cols
    constexpr int NWIN = WR * WC;       // 4160 records
    __shared__ __align__(16) char smem[40960];
    half4v* s_x = (half4v*)smem;                       // 4160 recs (33,280B)
    float*  s_t = (float*)smem;                        // 64 oc x 132 (33,792B, epilogue)
    half_t* s_o = (half_t*)(smem + 33792);             // 27 x 132 halfs (7,128B)

    const int tid   = threadIdx.x;
    const int lane  = tid & 63;
    const int wv    = tid >> 6;
    const int klane = lane >> 5;
    const int m     = lane & 31;
    const int zz    = blockIdx.x;       // (b,half): fastest axis -> XCD-partitioned
    const int b     = zz >> 1;
    const int dgbase = (zz & 1) * 8;
    const int tx0 = blockIdx.y * 32, ty0 = blockIdx.z * 4;
    const int py = ty0 + wv;
    const int px = tx0 + m;
    const int pixloc = wv * 32 + m;     // pixel index within the 4x32 tile

    const __half* offb = off4 + (size_t)b * 432 * HWSZ;

    f32x16 acc[2];
#pragma unroll
    for (int nt = 0; nt < 2; ++nt)
#pragma unroll
        for (int r = 0; r < 16; ++r) acc[nt][r] = 0.0f;

    for (int dgi = 0; dgi < 8; ++dgi) {
        const int dg = dgbase + dgi;
        const half_t* xdg = xTh + ((size_t)(dg * BB + b) * HWSZ) * 4;
        __syncthreads();                                   // prior dg reads done
        // stage x window (zero-padded)
        for (int i = tid; i < NWIN; i += 256) {
            int wr = i / WC, wc = i - wr * WC;
            int ry = ty0 - HLO + wr;
            int cx = tx0 - HLO + wc;
            half4v v = {};
            if ((unsigned)ry < (unsigned)HH && (unsigned)cx < (unsigned)WW)
                v = *(const half4v*)(xdg + ((size_t)ry * WW + cx) * 4);
            s_x[i] = v;
        }
        // stage off4 for this (tile, dg): planes 0..17 = offb[18dg+c],
        // planes 18..26 = offb[288+9dg+(c-18)]; 27 x 4row x 32px
        for (int i = tid; i < 27 * 16; i += 256) {
            int c = i >> 4, sub = i & 15;
            int row = sub >> 2, q = sub & 3;
            int gch = (c < 18) ? (18 * dg + c) : (288 + 9 * dg + (c - 18));
            const __half* src = offb + (size_t)gch * HWSZ + (ty0 + row) * WW + tx0 + q * 8;
            *(half8*)(s_o + c * 132 + row * 32 + q * 8) = *(const half8*)src;
        }
        __syncthreads();

        const half_t* bbase = Bp + (size_t)(dg * 3) * 64 * 16;
#pragma unroll
        for (int ks = 0; ks < 3; ++ks) {
            half2v svp[2][2] = {};
#pragma unroll
            for (int tt = 0; tt < 2; ++tt) {
                const int tap = ks * 4 + klane * 2 + tt;
                if (tap < 9) {
                    float oy = (float)s_o[(2*tap    ) * 132 + pixloc];
                    float ox = (float)s_o[(2*tap + 1) * 132 + pixloc];
                    float mk = (float)s_o[(18 + tap ) * 132 + pixloc];
                    float ys = (float)(py + tap / 3 - 1) + oy;
                    float xs = (float)(px + tap % 3 - 1) + ox;
                    float y0f = floorf(ys), x0f = floorf(xs);
                    float wy = ys - y0f,    wx = xs - x0f;
                    int y0 = (int)y0f, x0i = (int)x0f;
                    float a0 = (1.0f - wy) * mk, a1 = wy * mk;
                    float w00 = a0 * (1.0f - wx), w01 = a0 * wx;
                    float w10 = a1 * (1.0f - wx), w11 = a1 * wx;
                    const int wr0 = y0  - (ty0 - HLO);
                    const int wc0 = x0i - (tx0 - HLO);
                    half4v c00, c01, c10, c11;
                    if ((unsigned)wr0 < (unsigned)(WR - 1) &&
                        (unsigned)wc0 < (unsigned)(WC - 1)) {
                        const half4v* pw = s_x + wr0 * WC + wc0;
                        c00 = pw[0];  c01 = pw[1];
                        c10 = pw[WC]; c11 = pw[WC + 1];
                    } else {
                        int y1 = y0 + 1, x1 = x0i + 1;
                        float fy0 = (y0  >= 0 && y0  < HH) ? 1.0f : 0.0f;
                        float fy1 = (y1  >= 0 && y1  < HH) ? 1.0f : 0.0f;
                        float fx0 = (x0i >= 0 && x0i < WW) ? 1.0f : 0.0f;
                        float fx1 = (x1  >= 0 && x1  < WW) ? 1.0f : 0.0f;
                        int yc0 = min(max(y0, 0), HH-1), yc1 = min(max(y1, 0), HH-1);
                        int xc0 = min(max(x0i,0), WW-1), xc1 = min(max(x1, 0), WW-1);
                        w00 *= fy0 * fx0; w01 *= fy0 * fx1;
                        w10 *= fy1 * fx0; w11 *= fy1 * fx1;
                        c00 = *(const half4v*)(xdg + ((size_t)yc0 * WW + xc0) * 4);
                        c01 = *(const half4v*)(xdg + ((size_t)yc0 * WW + xc1) * 4);
                        c10 = *(const half4v*)(xdg + ((size_t)yc1 * WW + xc0) * 4);
                        c11 = *(const half4v*)(xdg + ((size_t)yc1 * WW + xc1) * 4);
                    }
                    half_t h00 = (half_t)w00, h01 = (half_t)w01;
                    half_t h10 = (half_t)w10, h11 = (half_t)w11;
                    half2v W00 = {h00, h00}, W01 = {h01, h01};
                    half2v W10 = {h10, h10}, W11 = {h11, h11};
                    half2v lo = __builtin_shufflevector(c00, c00, 0, 1) * W00
                              + __builtin_shufflevector(c01, c01, 0, 1) * W01
                              + __builtin_shufflevector(c10, c10, 0, 1) * W10
                              + __builtin_shufflevector(c11, c11, 0, 1) * W11;
                    half2v hi = __builtin_shufflevector(c00, c00, 2, 3) * W00
                              + __builtin_shufflevector(c01, c01, 2, 3) * W01
                              + __builtin_shufflevector(c10, c10, 2, 3) * W10
                              + __builtin_shufflevector(c11, c11, 2, 3) * W11;
                    svp[tt][0] = lo; svp[tt][1] = hi;
                }
            }
            half8 a;
            a[0] = svp[0][0][0]; a[1] = svp[0][0][1];
            a[2] = svp[0][1][0]; a[3] = svp[0][1][1];
            a[4] = svp[1][0][0]; a[5] = svp[1][0][1];
            a[6] = svp[1][1][0]; a[7] = svp[1][1][1];
            // consume immediately (short live range for the fragment)
#pragma unroll
            for (int nt = 0; nt < 2; ++nt) {
                half8 Bh = *(const half8*)(bbase + ((size_t)(ks*64 + nt*32 + m)) * 16 + klane*8);
                acc[nt] = __builtin_amdgcn_mfma_f32_32x32x16_f16(a, Bh, acc[nt], 0,0,0);
            }
        }
        __syncthreads();                                   // compute done before next stage
    }

    if (dgbase == 0) {
        // half0: +bias -> out fp32, staged through LDS for float4 stores
#pragma unroll
        for (int nt = 0; nt < 2; ++nt) {
            const int oc = nt * 32 + m;
            const float bv = bias[oc];
#pragma unroll
            for (int r = 0; r < 16; ++r) {
                const int row = (r & 3) + 8 * (r >> 2) + 4 * klane;   // px 0..31
                s_t[oc * 132 + wv * 32 + row] = acc[nt][r] + bv;
            }
        }
        __syncthreads();
        for (int c = tid; c < 2048; c += 256) {            // 64 oc x 4 row x 8 float4
            int ocl = c >> 5, rem = c & 31, row = rem >> 3, q = rem & 7;
            float4 v = *(const float4*)(s_t + ocl * 132 + row * 32 + q * 4);
            *(float4*)(out + ((size_t)(b*64 + ocl) << 14) + (ty0 + row) * 128 + tx0 + q * 4) = v;
        }
    } else {
        // half1: no bias -> p1h fp16 partial, coalesced half4 stores
#pragma unroll
        for (int nt = 0; nt < 2; ++nt) {
            const int oc = nt * 32 + m;
#pragma unroll
            for (int r = 0; r < 16; ++r) {
                const int row = (r & 3) + 8 * (r >> 2) + 4 * klane;
                s_t[oc * 132 + wv * 32 + row] = acc[nt][r];
            }
        }
        __syncthreads();
        for (int c = tid; c < 2048; c += 256) {
            int ocl = c >> 5, rem = c & 31, row = rem >> 3, q = rem & 7;
            float4 v = *(const float4*)(s_t + ocl * 132 + row * 32 + q * 4);
            half4v h = {(half_t)v.x, (half_t)v.y, (half_t)v.z, (half_t)v.w};
            *(half4v*)(p1h + ((size_t)(b*64 + ocl) << 14) + (ty0 + row) * 128 + tx0 + q * 4) = h;
        }
    }
}

// ---------------------------------------------------------------------------
// out += p1h (fp16 partial from dg half1). 42MB traffic, ~8us.
// ---------------------------------------------------------------------------
__global__ __launch_bounds__(256)
void add_partial_k(float* __restrict__ out, const half_t* __restrict__ p1h)
{
    const int N4 = BB * 64 * HWSZ / 4;                  // 1,048,576 quads
    for (int i = blockIdx.x * 256 + threadIdx.x; i < N4; i += gridDim.x * 256) {
        float4 o = *(const float4*)(out + (size_t)i * 4);
        half4v p = *(const half4v*)(p1h + (size_t)i * 4);
        o.x += (float)p[0]; o.y += (float)p[1];
        o.z += (float)p[2]; o.w += (float)p[3];
        *(float4*)(out + (size_t)i * 4) = o;
    }
}

// ---------------------------------------------------------------------------
// Workspace (~76 MB):
//   [0, 56.6MB)   off4h (fp16). Aliased during conv chain:
//       A0  @ +0      (19.5MB single-plane, live pack_a0..conv1)
//       h2p @ +0      (8.65MB single-plane, live conv2..conv3)
//   [56.6, 73.9MB) h1p region (h1p 8.65MB; after conv4: xTh (8.39MB) @ +0
//                  and p1h (8.39MB) @ +8.39MB)
//   [73.9MB, ...)  packed weights (wp1..wp4, Bp)
// ---------------------------------------------------------------------------
extern "C" void kernel_launch(void* const* d_in, const int* in_sizes, int n_in,
                              void* d_out, int out_size, void* d_ws, size_t ws_size,
                              hipStream_t stream)
{
    const float* x    = (const float*)d_in[0];
    const float* xfw  = (const float*)d_in[1];
    const float* xc   = (const float*)d_in[2];
    const float* flow = (const float*)d_in[3];
    const float* w1 = (const float*)d_in[4];  const float* b1 = (const float*)d_in[5];
    const float* w2 = (const float*)d_in[6];  const float* b2 = (const float*)d_in[7];
    const float* w3 = (const float*)d_in[8];  const float* b3 = (const float*)d_in[9];
    const float* w4 = (const float*)d_in[10]; const float* b4 = (const float*)d_in[11];
    const float* dw = (const float*)d_in[12]; const float* db = (const float*)d_in[13];

    char* wsb = (char*)d_ws;
    const size_t off4_bytes = (size_t)BB * 432 * HWSZ * 2;      // 56,623,104 (fp16)
    __half* off4 = (__half*)wsb;
    half_t* A0   = (half_t*)wsb;                                // live pack_a0..conv1
    half_t* h2p  = (half_t*)wsb;                                // live conv2..conv3
    char* p = wsb + off4_bytes;
    half_t* h1p = (half_t*)p;
    half_t* xTh = (half_t*)h1p;                                 // 8.39MB, post-conv4
    half_t* p1h = (half_t*)((char*)h1p + (size_t)BB * 64 * HWSZ * 2); // 8.39MB partial
                               p += (size_t)BB * PSZ * 2 * 64 * 2;     // region kept 17.3MB
    half_t* wp1 = (half_t*)p;  p += (size_t)64  * 144 * 9 * 2;
    half_t* wp2 = (half_t*)p;  p += (size_t)64  * 64  * 9 * 2;
    half_t* wp3 = (half_t*)p;  p += (size_t)64  * 64  * 9 * 2;
    half_t* wp4 = (half_t*)p;  p += (size_t)448 * 64  * 9 * 2;  // OCP=448 (OCB=64 x 7)
    half_t* Bp  = (half_t*)p;  p += (size_t)16 * 3 * 64 * 16 * 2;

    zero_border_k<<<(2064*8 + 255)/256, 256, 0, stream>>>(h1p);
    pack_w_k<<<(64*144*9 + 255)/256, 256, 0, stream>>>(w1, wp1, 64, 130, 64, 144, 9, 64);
    pack_w_k<<<(64*64*9  + 255)/256, 256, 0, stream>>>(w2, wp2, 64, 64, 64, 64, 4, 64);
    pack_w_k<<<(64*64*9  + 255)/256, 256, 0, stream>>>(w3, wp3, 64, 64, 64, 64, 4, 64);
    pack_w_k<<<(448*64*9 + 255)/256, 256, 0, stream>>>(w4, wp4, 432, 64, 448, 64, 4, 64);
    pack_dw_k<<<(16*3*64*16 + 255)/256, 256, 0, stream>>>(dw, Bp);
    pack_a0_k<<<(BB*PSZ + 63)/64, 256, 0, stream>>>(xfw, xc, flow, A0);

    // conv chain: conv1-3 MT=1 NT=2 (256,4); conv4 MT=1 NT=2 z=7 (256,8)
    conv_mfma_k<144,1,0,2><<<dim3(128, BB, 1), 256, 0, stream>>>(A0,  wp1, b1, h1p, 64,  nullptr);
    zero_border_k<<<(2064*8 + 255)/256, 256, 0, stream>>>(h2p);    // A0 dead now
    conv_mfma_k<64, 1,0,2><<<dim3(128, BB, 1), 256, 0, stream>>>(h1p, wp2, b2, h2p, 64,  nullptr);
    conv_mfma_k<64, 1,0,2><<<dim3(128, BB, 1), 256, 0, stream>>>(h2p, wp3, b3, h1p, 64,  nullptr);
    conv_mfma_k<64, 1,1,2><<<dim3(128, BB, 7), 256, 0, stream>>>(h1p, wp4, b4, off4, 432, flow);
    // xTh overwrites h1p (dead after conv4)
    pack_xt_k<<<BB * HWSZ / 64, 256, 0, stream>>>(x, xTh);

    // dcn: (b,half) on blockIdx.x -> one XCD per (b,half); tiles on y/z
    dcn_mfma_k<<<dim3(BB*2, 4, 32), 256, 0, stream>>>(xTh, off4, Bp, db, (float*)d_out, p1h);
    add_partial_k<<<2048, 256, 0, stream>>>((float*)d_out, p1h);
}